// Round 4
// baseline (426.632 us; speedup 1.0000x reference)
//
#include <hip/hip_runtime.h>

// ---------------------------------------------------------------------------
// Session history:
//  R1: atomic dump to L3-resident out = 135 us (cross-XCD atomic RMW serializes
//      at the coherence point). Keep streaming partials.
//  R2: ballot-aggregated scnt alloc = neutral. R3: batched DS atomics = neutral.
//      -> bin's store path is not the bottleneck.
//  R0-R3 accounting: {fill 41, pack 1.5, bin ~38, agg 10, red 6, GAP ~13/dispatch}
//      fits R0->R1 delta and R3 absolute exactly. 40% of runtime = dispatch gaps.
//  R4 (this): single megakernel, 2 dispatches/iter. Inter-block sync via
//      poison-immune (v,~v) pair flags (no init needed under re-poison).
// ---------------------------------------------------------------------------

#define TPB_PACK  256
#define P1_BLOCKS 512
#define P1_TPB    1024
#define SB_BITS   14
#define SBS       (1 << SB_BITS)     // atoms per super-bucket (16384)
#define NS_MEGA   13                 // mega path: natoms <= 13*16384 = 212992
#define NS_MAX    16
#define P2_TPB    1024
#define R_SUB     39                 // 13*39=507 agg work items
#define TPB_RED   256
#define CAP_MAX   1024

// log-spaced energy table: r = 2^(L0 + k*HL), k in [0,256]; 258 entries/type (pad)
#define TAB_N   258
#define TAB_L0  (-3.3219281f)        // log2(0.1)
#define TAB_HL  (0.017157490f)       // (log2(2.1)-log2(0.1))/256
#define TAB_INV (58.283567f)         // 1/TAB_HL
#define TAB_OFF (193.61423f)         // -L0*TAB_INV

typedef unsigned long long u64;

// ---- poison-immune value-carrying flags: (v, ~v) pairs -----------------------
// ws is re-poisoned each iteration with a uniform pattern P: (P,P) never
// satisfies hi==~lo (x==~x impossible), zeros (0,0) are invalid too. So no
// initialization pass is ever needed. Values travel device-scope (sc1).
__device__ __forceinline__ void pub_pair(u64* p, unsigned v) {
    u64 w = (u64)v | ((u64)(~v) << 32);
    __hip_atomic_store(p, w, __ATOMIC_RELAXED, __HIP_MEMORY_SCOPE_AGENT);
}
__device__ __forceinline__ unsigned spin_pair(u64* p) {
    for (;;) {
        u64 w = __hip_atomic_load(p, __ATOMIC_RELAXED, __HIP_MEMORY_SCOPE_AGENT);
        if ((unsigned)(w >> 32) == ~(unsigned)w) return (unsigned)w;
        __builtin_amdgcn_s_sleep(1);
    }
}

// =============================================================================
// MEGAKERNEL: pack -> bin -> agg -> red in one dispatch.
// Grid MUST be 512 blocks, all co-resident: LDS ~70.4KB -> 2 blocks/CU;
// __launch_bounds__(1024,8) caps VGPR<=64 so 2x16 waves fit per CU. 2*256=512.
// =============================================================================
__global__ __launch_bounds__(P1_TPB, 8) void zbl_mega(
    const float* __restrict__ rij,
    const float* __restrict__ rcov,
    const float* __restrict__ znum,
    const int*  __restrict__ fa,
    const int*  __restrict__ sa,
    const int*  __restrict__ types,
    u64*  __restrict__ packed2,      // [nwords] (word,~word) pairs
    u64*  __restrict__ counts2,      // [NS][P1_BLOCKS] (cnt,~cnt) pairs
    u64*  __restrict__ ovfc2,        // [P1_BLOCKS] overflow-count pairs
    u64*  __restrict__ done2,        // [NS*R_SUB] dump-done pairs
    unsigned int* __restrict__ regions, // [P1_BLOCKS][NS][cap]
    uint2* __restrict__ ovf,         // [P1_BLOCKS][ovfStride] {e, atom}
    float* __restrict__ partials,    // [NS][R_SUB][SBS]
    float* __restrict__ out,
    int E, int nquad, int natoms, int nwords, int NS, int cap, int chunkQ,
    int ovfStride)
{
    __shared__ union {
        struct { unsigned pk[NS_MEGA * SBS / 16]; float tabE[16 * TAB_N]; } a; // 69.8 KB
        float  acc[SBS];                                                       // 64 KB
        float4 acc4[SBS / 4];
    } u;
    __shared__ float4 cB[16];
    __shared__ float4 cS[16];
    __shared__ float  cC[16];
    __shared__ int    scnt[NS_MAX];
    __shared__ int    s_ovfn;
    __shared__ int    s_anyovf;

    const int b   = blockIdx.x;
    const int tid = threadIdx.x;

    // ---------------- phase 0: cooperative type-pack (publish pairs) ---------
    {
        int wpb = (nwords + P1_BLOCKS - 1) / P1_BLOCKS;
        int w0 = b * wpb, w1 = w0 + wpb; if (w1 > nwords) w1 = nwords;
        for (int w = w0 + tid; w < w1; w += P1_TPB) {
            int base = w << 4;
            unsigned word = 0;
            #pragma unroll
            for (int j = 0; j < 16; ++j) {
                int i = base + j;
                unsigned t = (i < natoms) ? (unsigned)types[i] : 0u;
                word |= (t & 3u) << (2 * j);
            }
            pub_pair(&packed2[w], word);   // value-carrying flag, no fence needed
        }
    }

    if (tid < NS)  scnt[tid] = 0;
    if (tid == 32) s_ovfn = 0;

    // per-pair constants (16 threads; overlaps other threads' pk spin-load)
    if (tid < 16) {
        const float cc[4] = {0.02817f, 0.28022f, 0.50986f, 0.18175f};
        const float dd[4] = {0.20162f, 0.4029f, 0.94229f, 3.1998f};
        const float COUL = 14.399645478425668f;
        int t = tid;
        int ti = t >> 2, tj = t & 3;
        float zi = znum[ti], zj = znum[tj];
        float rc = rcov[ti] + rcov[tj];
        float a = 0.4685f / (powf(zi, 0.23f) + powf(zj, 0.23f));
        float inva = 1.0f / a;
        float factor = COUL * zi * zj;
        float da[4], ee[4];
        float phi = 0.0f, dphi = 0.0f, d2phi = 0.0f;
        #pragma unroll
        for (int k = 0; k < 4; ++k) {
            da[k] = dd[k] * inva;
            ee[k] = expf(-rc * da[k]);
            phi   += cc[k] * ee[k];
            dphi  -= cc[k] * da[k] * ee[k];
            d2phi += cc[k] * da[k] * da[k] * ee[k];
        }
        float invrc = 1.0f / rc;
        float ec   = factor * invrc * phi;
        float dec  = factor * invrc * (-phi * invrc + dphi);
        float d2ec = factor * invrc * (d2phi - 2.0f * invrc * dphi + 2.0f * phi * invrc * invrc);
        float A = (-3.0f * dec + rc * d2ec) * invrc * invrc;
        float B = (2.0f * dec - rc * d2ec) * invrc * invrc * invrc;
        float Cc = -ec + 0.5f * rc * dec - rc * rc * d2ec * (1.0f / 12.0f);
        const float L2E = 1.4426950408889634f;
        cB[t] = make_float4(rc, 0.5f * factor, A * (1.0f / 6.0f), B * 0.125f);
        cS[t] = make_float4(-da[0] * L2E, -da[1] * L2E, -da[2] * L2E, -da[3] * L2E);
        cC[t] = Cc * 0.5f;
    }

    // spin-load all packed words into LDS (value IS the flag)
    for (int w = tid; w < nwords; w += P1_TPB)
        u.a.pk[w] = spin_pair(&packed2[w]);
    __syncthreads();

    const float lc0 = -5.1497481f;   // log2(0.02817)
    const float lc1 = -1.8353434f;   // log2(0.28022)
    const float lc2 = -0.9718340f;   // log2(0.50986)
    const float lc3 = -2.4600449f;   // log2(0.18175)

    // build per-type energy table
    for (int n = tid; n < 16 * TAB_N; n += P1_TPB) {
        int t = n / TAB_N, k = n - t * TAB_N;
        float v = 0.0f;
        if (k <= 256) {
            float r = exp2f(__builtin_fmaf((float)k, TAB_HL, TAB_L0));
            float4 B = cB[t];
            if (r <= B.x) {
                float4 S = cS[t];
                float p = exp2f(__builtin_fmaf(r, S.x, lc0))
                        + exp2f(__builtin_fmaf(r, S.y, lc1))
                        + exp2f(__builtin_fmaf(r, S.z, lc2))
                        + exp2f(__builtin_fmaf(r, S.w, lc3));
                float r3 = r * r * r;
                float poly = __builtin_fmaf(__builtin_fmaf(B.w, r, B.z), r3, cC[t]);
                v = __builtin_fmaf(B.y * p, 1.0f / r, poly);
            }
        }
        u.a.tabE[n] = v;
    }
    __syncthreads();

    // ---------------- phase 1: bin (tabulated e, record scatter) -------------
    {
        const float4* rij4 = (const float4*)rij;
        const int4*   fa4  = (const int4*)fa;
        const int4*   sa4  = (const int4*)sa;
        int myreg = b * NS;
        int q0 = b * chunkQ;
        int q1 = q0 + chunkQ; if (q1 > nquad) q1 = nquad;

        for (int q = q0 + tid; q < q1; q += P1_TPB) {
            float4 rv = rij4[q];
            int4   iv = fa4[q];
            int4   jv = sa4[q];
            float ra[4] = {rv.x, rv.y, rv.z, rv.w};
            int   ia[4] = {iv.x, iv.y, iv.z, iv.w};
            int   ja[4] = {jv.x, jv.y, jv.z, jv.w};
            float eo[4];
            #pragma unroll
            for (int k = 0; k < 4; ++k) {
                int i = ia[k], j = ja[k];
                unsigned wi = u.a.pk[i >> 4], wj = u.a.pk[j >> 4];
                unsigned ti = (wi >> ((i & 15) * 2)) & 3u;
                unsigned tj = (wj >> ((j & 15) * 2)) & 3u;
                int t = (int)((ti << 2) | tj);
                float kf = __builtin_fmaf(__log2f(ra[k]), TAB_INV, TAB_OFF);
                int ki = (int)kf;
                ki = ki < 0 ? 0 : (ki > 256 ? 256 : ki);
                float frac = kf - (float)ki;
                int base = t * TAB_N + ki;
                float v0 = u.a.tabE[base];
                float v1 = u.a.tabE[base + 1];
                eo[k] = __builtin_fmaf(v1 - v0, frac, v0);
            }
            #pragma unroll
            for (int k = 0; k < 4; ++k) {
                if (eo[k] != 0.0f) {
                    int atom = ia[k];
                    int s = atom >> SB_BITS;
                    int slot = atomicAdd(&scnt[s], 1);
                    if (slot < cap) {
                        unsigned rec = ((__float_as_uint(eo[k]) + 0x2000u) & 0xFFFFC000u)
                                     | (unsigned)(atom & (SBS - 1));
                        regions[(myreg + s) * cap + slot] = rec;
                    } else {
                        int o = atomicAdd(&s_ovfn, 1);     // block-local list, no init
                        ovf[(size_t)b * ovfStride + o] =
                            make_uint2(__float_as_uint(eo[k]), (unsigned)atom);
                    }
                }
            }
        }

        // tail edges (E % 4): block 0, into its overflow list
        if (b == 0) {
            for (int idx = nquad * 4 + tid; idx < E; idx += P1_TPB) {
                int i = fa[idx], j = sa[idx];
                unsigned wi = u.a.pk[i >> 4], wj = u.a.pk[j >> 4];
                int t = (int)((((wi >> ((i & 15) * 2)) & 3u) << 2) |
                               ((wj >> ((j & 15) * 2)) & 3u));
                float r = rij[idx];
                float kf = __builtin_fmaf(__log2f(r), TAB_INV, TAB_OFF);
                int ki = (int)kf;
                ki = ki < 0 ? 0 : (ki > 256 ? 256 : ki);
                float frac = kf - (float)ki;
                int base = t * TAB_N + ki;
                float e = __builtin_fmaf(u.a.tabE[base + 1] - u.a.tabE[base], frac,
                                         u.a.tabE[base]);
                if (e != 0.0f) {
                    int o = atomicAdd(&s_ovfn, 1);
                    ovf[(size_t)b * ovfStride + o] =
                        make_uint2(__float_as_uint(e), (unsigned)i);
                }
            }
        }

        // publish: fence (wbl2 -> records visible at coherence point), then flags
        __syncthreads();
        if (tid == 0) __threadfence();
        __syncthreads();
        if (tid < NS)  pub_pair(&counts2[tid * P1_BLOCKS + b],
                                (unsigned)min(scnt[tid], cap));
        if (tid == NS) pub_pair(&ovfc2[b], (unsigned)s_ovfn);
    }

    // ---------------- phase 2: agg (b < NS*R_SUB) ---------------------------
    // Consumers spin per-producer on counts2 pairs -> natural overlap with
    // stragglers still finishing phase 1. Requires all blocks resident (they are).
    if (b < NS * R_SUB) {
        int s = b / R_SUB, r = b % R_SUB;
        __syncthreads();                       // everyone done with pk/tabE
        for (int i = tid; i < SBS / 4; i += P1_TPB)
            u.acc4[i] = make_float4(0.f, 0.f, 0.f, 0.f);
        __syncthreads();

        int wave = tid >> 6;
        int lane = tid & 63;
        const int NW = P1_TPB >> 6;            // 16 waves
        for (int p = r + wave * R_SUB; p < P1_BLOCKS; p += NW * R_SUB) {
            unsigned n = spin_pair(&counts2[s * P1_BLOCKS + p]);   // wave-uniform
            __threadfence();                   // acquire: fresh view of records
            int base = (p * NS + s) * cap;
            for (int t = lane; t < (int)n; t += 64) {
                unsigned rec = regions[base + t];
                atomicAdd(&u.acc[rec & (SBS - 1)],
                          __uint_as_float(rec & 0xFFFFC000u));
            }
        }
        __syncthreads();

        float4* dst4 = (float4*)(partials + ((size_t)s * R_SUB + r) * SBS);
        for (int i = tid; i < SBS / 4; i += P1_TPB)
            dst4[i] = u.acc4[i];
        __syncthreads();
        if (tid == 0) {
            __threadfence();                   // flush partials to coherence point
            pub_pair(&done2[b], 1u);
        }
    }

    // ---------------- phase 3: slice reduction -> out ------------------------
    {
        // wait for all dumps (parallel spin over 507 flags)
        for (int i = tid; i < NS * R_SUB; i += P1_TPB)
            (void)spin_pair(&done2[i]);
        __syncthreads();
        if (tid == 0) __threadfence();         // acquire for partials reads
        __syncthreads();

        int nq  = natoms >> 2;
        int qpb = (nq + P1_BLOCKS - 1) / P1_BLOCKS;
        int qlo = b * qpb, qhi = qlo + qpb; if (qhi > nq) qhi = nq;
        int alo = qlo << 2, ahi = qhi << 2;

        for (int q = qlo + tid; q < qhi; q += P1_TPB) {
            int atom = q << 2;
            int s = atom >> SB_BITS, i = atom & (SBS - 1);
            const float* p = partials + (size_t)s * R_SUB * SBS + i;
            float4 acc = make_float4(0.f, 0.f, 0.f, 0.f);
            #pragma unroll
            for (int k = 0; k < R_SUB; ++k) {
                float4 v = *(const float4*)(p + (size_t)k * SBS);
                acc.x += v.x; acc.y += v.y; acc.z += v.z; acc.w += v.w;
            }
            *(float4*)(out + atom) = acc;
        }
        // scalar tail atoms -> owned by last block
        bool own_tail = (b == P1_BLOCKS - 1);
        if (own_tail) {
            for (int atom = (nq << 2) + tid; atom < natoms; atom += P1_TPB) {
                int s = atom >> SB_BITS, i = atom & (SBS - 1);
                const float* p = partials + (size_t)s * R_SUB * SBS + i;
                float acc = 0.f;
                #pragma unroll
                for (int k = 0; k < R_SUB; ++k) acc += p[(size_t)k * SBS];
                out[atom] = acc;
            }
        }

        // overflow application (typical count: 0). Each block applies only
        // entries in its own atom range -> no cross-block write conflicts.
        if (tid == 0) s_anyovf = 0;
        __syncthreads();
        for (int p0 = tid; p0 < P1_BLOCKS; p0 += P1_TPB) {
            unsigned n = spin_pair(&ovfc2[p0]);
            if (n) atomicAdd(&s_anyovf, (int)n);
        }
        __syncthreads();
        if (s_anyovf > 0) {                    // rare, correctness-only path
            for (int p = 0; p < P1_BLOCKS; ++p) {
                unsigned n = spin_pair(&ovfc2[p]);
                const uint2* lst = ovf + (size_t)p * ovfStride;
                for (int e = tid; e < (int)n; e += P1_TPB) {
                    uint2 rec = lst[e];
                    int atom = (int)rec.y;
                    bool mine = (atom >= alo && atom < ahi) ||
                                (own_tail && atom >= (nq << 2) && atom < natoms);
                    if (mine) unsafeAtomicAdd(&out[atom], __uint_as_float(rec.x));
                }
            }
        }
    }
}

// =============================================================================
// LEGACY PATH (natoms > 212992 or tiny ws): known-good 4-kernel pipeline (R3).
// =============================================================================
__global__ __launch_bounds__(TPB_PACK) void zbl_pack(
    const int* __restrict__ types, unsigned int* __restrict__ packed,
    float* __restrict__ fallback, int natoms, int nwords)
{
    int tid = blockIdx.x * TPB_PACK + threadIdx.x;
    int nth = gridDim.x * TPB_PACK;
    for (int w = tid; w < nwords; w += nth) {
        int base = w << 4;
        unsigned int word = 0;
        #pragma unroll
        for (int j = 0; j < 16; ++j) {
            int i = base + j;
            unsigned int t = (i < natoms) ? (unsigned int)types[i] : 0u;
            word |= (t & 3u) << (2 * j);
        }
        packed[w] = word;
    }
    for (int i = tid; i < natoms; i += nth) fallback[i] = 0.0f;
}

__global__ __launch_bounds__(P1_TPB) void zbl_bin(
    const float* __restrict__ rij, const float* __restrict__ rcov,
    const float* __restrict__ znum, const int* __restrict__ fa,
    const int* __restrict__ sa, const unsigned int* __restrict__ packed,
    unsigned int* __restrict__ regions, int* __restrict__ counts,
    float* __restrict__ fallback,
    int E, int nquad, int natoms, int nwords, int NS, int cap, int chunkQ)
{
    extern __shared__ unsigned int s_packed[];
    __shared__ float  tabE[16 * TAB_N];
    __shared__ float4 cB[16];
    __shared__ float4 cS[16];
    __shared__ float  cC[16];
    __shared__ int scnt[NS_MAX];

    for (int w = threadIdx.x; w < nwords; w += P1_TPB) s_packed[w] = packed[w];
    if (threadIdx.x < NS) scnt[threadIdx.x] = 0;

    if (threadIdx.x < 16) {
        const float cc[4] = {0.02817f, 0.28022f, 0.50986f, 0.18175f};
        const float dd[4] = {0.20162f, 0.4029f, 0.94229f, 3.1998f};
        const float COUL = 14.399645478425668f;
        int t = threadIdx.x;
        int ti = t >> 2, tj = t & 3;
        float zi = znum[ti], zj = znum[tj];
        float rc = rcov[ti] + rcov[tj];
        float a = 0.4685f / (powf(zi, 0.23f) + powf(zj, 0.23f));
        float inva = 1.0f / a;
        float factor = COUL * zi * zj;
        float da[4], ee[4];
        float phi = 0.0f, dphi = 0.0f, d2phi = 0.0f;
        #pragma unroll
        for (int k = 0; k < 4; ++k) {
            da[k] = dd[k] * inva;
            ee[k] = expf(-rc * da[k]);
            phi   += cc[k] * ee[k];
            dphi  -= cc[k] * da[k] * ee[k];
            d2phi += cc[k] * da[k] * da[k] * ee[k];
        }
        float invrc = 1.0f / rc;
        float ec   = factor * invrc * phi;
        float dec  = factor * invrc * (-phi * invrc + dphi);
        float d2ec = factor * invrc * (d2phi - 2.0f * invrc * dphi + 2.0f * phi * invrc * invrc);
        float A = (-3.0f * dec + rc * d2ec) * invrc * invrc;
        float B = (2.0f * dec - rc * d2ec) * invrc * invrc * invrc;
        float Cc = -ec + 0.5f * rc * dec - rc * rc * d2ec * (1.0f / 12.0f);
        const float L2E = 1.4426950408889634f;
        cB[t] = make_float4(rc, 0.5f * factor, A * (1.0f / 6.0f), B * 0.125f);
        cS[t] = make_float4(-da[0] * L2E, -da[1] * L2E, -da[2] * L2E, -da[3] * L2E);
        cC[t] = Cc * 0.5f;
    }
    __syncthreads();

    const float lc0 = -5.1497481f, lc1 = -1.8353434f;
    const float lc2 = -0.9718340f, lc3 = -2.4600449f;

    for (int n = threadIdx.x; n < 16 * TAB_N; n += P1_TPB) {
        int t = n / TAB_N, k = n - t * TAB_N;
        float v = 0.0f;
        if (k <= 256) {
            float r = exp2f(__builtin_fmaf((float)k, TAB_HL, TAB_L0));
            float4 B = cB[t];
            if (r <= B.x) {
                float4 S = cS[t];
                float p = exp2f(__builtin_fmaf(r, S.x, lc0))
                        + exp2f(__builtin_fmaf(r, S.y, lc1))
                        + exp2f(__builtin_fmaf(r, S.z, lc2))
                        + exp2f(__builtin_fmaf(r, S.w, lc3));
                float r3 = r * r * r;
                float poly = __builtin_fmaf(__builtin_fmaf(B.w, r, B.z), r3, cC[t]);
                v = __builtin_fmaf(B.y * p, 1.0f / r, poly);
            }
        }
        tabE[n] = v;
    }
    __syncthreads();

    const float4* rij4 = (const float4*)rij;
    const int4*   fa4  = (const int4*)fa;
    const int4*   sa4  = (const int4*)sa;
    int myreg = blockIdx.x * NS;
    int q0 = blockIdx.x * chunkQ;
    int q1 = q0 + chunkQ; if (q1 > nquad) q1 = nquad;

    for (int q = q0 + threadIdx.x; q < q1; q += P1_TPB) {
        float4 rv = rij4[q];
        int4   iv = fa4[q];
        int4   jv = sa4[q];
        float ra[4] = {rv.x, rv.y, rv.z, rv.w};
        int   ia[4] = {iv.x, iv.y, iv.z, iv.w};
        int   ja[4] = {jv.x, jv.y, jv.z, jv.w};
        float eo[4];
        #pragma unroll
        for (int k = 0; k < 4; ++k) {
            int i = ia[k], j = ja[k];
            unsigned int wi = s_packed[i >> 4], wj = s_packed[j >> 4];
            unsigned int ti = (wi >> ((i & 15) * 2)) & 3u;
            unsigned int tj = (wj >> ((j & 15) * 2)) & 3u;
            int t = (int)((ti << 2) | tj);
            float kf = __builtin_fmaf(__log2f(ra[k]), TAB_INV, TAB_OFF);
            int ki = (int)kf;
            ki = ki < 0 ? 0 : (ki > 256 ? 256 : ki);
            float frac = kf - (float)ki;
            int base = t * TAB_N + ki;
            float v0 = tabE[base], v1 = tabE[base + 1];
            eo[k] = __builtin_fmaf(v1 - v0, frac, v0);
        }
        #pragma unroll
        for (int k = 0; k < 4; ++k) {
            if (eo[k] != 0.0f) {
                int atom = ia[k];
                int s = atom >> SB_BITS;
                int slot = atomicAdd(&scnt[s], 1);
                if (slot < cap) {
                    unsigned rec = ((__float_as_uint(eo[k]) + 0x2000u) & 0xFFFFC000u)
                                 | (unsigned)(atom & (SBS - 1));
                    regions[(unsigned)((myreg + s) * cap + slot)] = rec;
                } else {
                    unsafeAtomicAdd(&fallback[atom], eo[k]);
                }
            }
        }
    }

    if (blockIdx.x == 0) {
        for (int idx = nquad * 4 + threadIdx.x; idx < E; idx += P1_TPB) {
            int i = fa[idx], j = sa[idx];
            unsigned int wi = s_packed[i >> 4], wj = s_packed[j >> 4];
            int t = (int)((((wi >> ((i & 15) * 2)) & 3u) << 2) |
                           ((wj >> ((j & 15) * 2)) & 3u));
            float r = rij[idx];
            float kf = __builtin_fmaf(__log2f(r), TAB_INV, TAB_OFF);
            int ki = (int)kf;
            ki = ki < 0 ? 0 : (ki > 256 ? 256 : ki);
            float frac = kf - (float)ki;
            int base = t * TAB_N + ki;
            float e = __builtin_fmaf(tabE[base + 1] - tabE[base], frac, tabE[base]);
            if (e != 0.0f) unsafeAtomicAdd(&fallback[i], e);
        }
    }

    __syncthreads();
    if (cap > 0 && threadIdx.x < NS)
        counts[threadIdx.x * P1_BLOCKS + blockIdx.x] = min(scnt[threadIdx.x], cap);
}

__global__ __launch_bounds__(P2_TPB) void zbl_agg(
    const unsigned int* __restrict__ regions, const int* __restrict__ counts,
    float* __restrict__ partials, int NS, int cap)
{
    __shared__ float acc[SBS];
    int s = blockIdx.x, r = blockIdx.y;
    float4* acc4 = (float4*)acc;
    for (int i = threadIdx.x; i < SBS / 4; i += P2_TPB)
        acc4[i] = make_float4(0.f, 0.f, 0.f, 0.f);
    __syncthreads();
    int wave = threadIdx.x >> 6, lane = threadIdx.x & 63;
    const int NW = P2_TPB >> 6;
    for (int p = r + wave * R_SUB; p < P1_BLOCKS; p += NW * R_SUB) {
        int n = counts[s * P1_BLOCKS + p];
        size_t base = ((size_t)p * NS + s) * (size_t)cap;
        for (int t = lane; t < n; t += 64) {
            unsigned rec = regions[base + t];
            atomicAdd(&acc[rec & (SBS - 1)], __uint_as_float(rec & 0xFFFFC000u));
        }
    }
    __syncthreads();
    float4* dst4 = (float4*)(partials + ((size_t)s * R_SUB + r) * SBS);
    for (int i = threadIdx.x; i < SBS / 4; i += P2_TPB)
        dst4[i] = acc4[i];
}

__global__ __launch_bounds__(TPB_RED) void zbl_red(
    const float* __restrict__ partials, const float* __restrict__ fallback,
    float* __restrict__ out, int natoms)
{
    int q = blockIdx.x * TPB_RED + threadIdx.x;
    int nq = natoms >> 2;
    if (q < nq) {
        int atom = q << 2;
        int s = atom >> SB_BITS, i = atom & (SBS - 1);
        const float4* fb4 = (const float4*)(fallback + atom);
        float4 acc = *fb4;
        const float* p = partials + (size_t)s * R_SUB * SBS + i;
        #pragma unroll
        for (int k = 0; k < R_SUB; ++k) {
            float4 v = *(const float4*)(p + (size_t)k * SBS);
            acc.x += v.x; acc.y += v.y; acc.z += v.z; acc.w += v.w;
        }
        *(float4*)(out + atom) = acc;
    }
    if (blockIdx.x == 0 && threadIdx.x < (natoms & 3)) {
        int atom = (nq << 2) + threadIdx.x;
        int s = atom >> SB_BITS, i = atom & (SBS - 1);
        float acc = fallback[atom];
        const float* p = partials + (size_t)s * R_SUB * SBS + i;
        #pragma unroll
        for (int k = 0; k < R_SUB; ++k) acc += p[(size_t)k * SBS];
        out[atom] = acc;
    }
}

// =============================================================================
static inline size_t al256(size_t x) { return (x + 255) & ~(size_t)255; }

extern "C" void kernel_launch(void* const* d_in, const int* in_sizes, int n_in,
                              void* d_out, int out_size, void* d_ws, size_t ws_size,
                              hipStream_t stream) {
    const float* rij  = (const float*)d_in[0];
    const float* rcov = (const float*)d_in[1];
    const float* znum = (const float*)d_in[2];
    const int*   fa   = (const int*)d_in[3];
    const int*   sa   = (const int*)d_in[4];
    const int*   types= (const int*)d_in[5];
    float* out = (float*)d_out;
    int E = in_sizes[0];
    int natoms = out_size;
    int nquad = E / 4;
    int nwords = (natoms + 15) / 16;
    int NS = (natoms + SBS - 1) >> SB_BITS;
    if (NS > NS_MAX) NS = NS_MAX;
    int chunkQ = (nquad + P1_BLOCKS - 1) / P1_BLOCKS;
    int ovfStride = chunkQ * 4 + 8;

    if (natoms <= NS_MEGA * SBS) {
        // --- mega layout: [packed2][counts2][ovfc2][done2][partials][ovf][regions]
        size_t packed2_b = al256((size_t)nwords * 8);
        size_t counts2_b = al256((size_t)NS * P1_BLOCKS * 8);
        size_t ovfc2_b   = al256((size_t)P1_BLOCKS * 8);
        size_t done2_b   = al256((size_t)NS * R_SUB * 8);
        size_t part_b    = al256((size_t)NS * R_SUB * SBS * 4);
        size_t ovf_b     = al256((size_t)P1_BLOCKS * ovfStride * 8);
        char* base = (char*)d_ws;
        u64*  packed2 = (u64*)base;                          base += packed2_b;
        u64*  counts2 = (u64*)base;                          base += counts2_b;
        u64*  ovfc2   = (u64*)base;                          base += ovfc2_b;
        u64*  done2   = (u64*)base;                          base += done2_b;
        float* partials = (float*)base;                      base += part_b;
        uint2* ovf    = (uint2*)base;                        base += ovf_b;
        unsigned int* regions = (unsigned int*)base;

        long long avail = (long long)ws_size
            - (long long)(packed2_b + counts2_b + ovfc2_b + done2_b + part_b + ovf_b);
        int cap = 0;
        if (avail > 0) cap = (int)(avail / ((long long)P1_BLOCKS * NS * 4));
        if (cap > CAP_MAX) cap = CAP_MAX;

        if (cap >= 64) {
            zbl_mega<<<P1_BLOCKS, P1_TPB, 0, stream>>>(
                rij, rcov, znum, fa, sa, types,
                packed2, counts2, ovfc2, done2, regions, ovf, partials, out,
                E, nquad, natoms, nwords, NS, cap, chunkQ, ovfStride);
            return;
        }
        // fall through to legacy if ws too small
    }

    // --- legacy layout: [packed][counts][fallback][partials][regions]
    size_t packed_bytes = al256((size_t)nwords * 4);
    size_t cnt_bytes    = al256((size_t)NS * P1_BLOCKS * 4);
    size_t fb_bytes     = al256((size_t)natoms * 4);
    size_t part_bytes   = al256((size_t)NS * R_SUB * SBS * 4);
    unsigned int* packed = (unsigned int*)d_ws;
    int*   counts   = (int*)  ((char*)d_ws + packed_bytes);
    float* fallback = (float*)((char*)d_ws + packed_bytes + cnt_bytes);
    float* partials = (float*)((char*)d_ws + packed_bytes + cnt_bytes + fb_bytes);
    unsigned int* regions = (unsigned int*)((char*)d_ws + packed_bytes + cnt_bytes
                                            + fb_bytes + part_bytes);
    long long avail = (long long)ws_size
                    - (long long)(packed_bytes + cnt_bytes + fb_bytes + part_bytes);
    int cap = 0;
    if (avail > 0) cap = (int)(avail / ((long long)P1_BLOCKS * (long long)NS * 4));
    if (cap > CAP_MAX) cap = CAP_MAX;
    size_t smem = (size_t)nwords * sizeof(unsigned int);

    if (cap >= 64) {
        zbl_pack<<<96, TPB_PACK, 0, stream>>>(types, packed, fallback, natoms, nwords);
        zbl_bin<<<P1_BLOCKS, P1_TPB, smem, stream>>>(
            rij, rcov, znum, fa, sa, packed, regions, counts, fallback,
            E, nquad, natoms, nwords, NS, cap, chunkQ);
        dim3 g2(NS, R_SUB);
        zbl_agg<<<g2, P2_TPB, 0, stream>>>(regions, counts, partials, NS, cap);
        int nq = natoms >> 2;
        zbl_red<<<(nq + TPB_RED - 1) / TPB_RED, TPB_RED, 0, stream>>>(
            partials, fallback, out, natoms);
    } else {
        zbl_pack<<<96, TPB_PACK, 0, stream>>>(types, packed, out, natoms, nwords);
        zbl_bin<<<P1_BLOCKS, P1_TPB, smem, stream>>>(
            rij, rcov, znum, fa, sa, packed, regions, counts, out,
            E, nquad, natoms, nwords, NS, 0, chunkQ);
    }
}

// Round 5
// 228.548 us; speedup vs baseline: 1.8667x; 1.8667x over previous
//
#include <hip/hip_runtime.h>

// ---------------------------------------------------------------------------
// Session history:
//  R1: atomic dump to L3-resident out = 135 us (cross-XCD atomic RMW serializes
//      at the coherence point). Keep streaming partials.
//  R2/R3: scnt-alloc variants neutral -> bin store path not the bottleneck.
//  R0-R3 accounting: {fill 41, pack 1.5, bin ~38, agg 10, red 6, GAP ~13/disp}.
//      40% of runtime = dispatch gaps -> megakernel.
//  R4: mega worked (96% occ, passed) but 354 us: SPIN STORM — every thread
//      polling agent-scope flags at s_sleep(1) saturated the LLC/fabric.
//  R5 (this): same mega skeleton, polling cut ~99%: plain counts + single
//      bin barrier (wave0 polls 512 pair-flags), per-bucket agg wait.
// ---------------------------------------------------------------------------

#define TPB_PACK  256
#define P1_BLOCKS 512
#define P1_TPB    1024
#define SB_BITS   14
#define SBS       (1 << SB_BITS)     // atoms per super-bucket (16384)
#define NS_MEGA   13                 // mega path: natoms <= 13*16384 = 212992
#define NS_MAX    16
#define P2_TPB    1024
#define R_SUB     39                 // 13*39=507 agg work items
#define TPB_RED   256
#define CAP_MAX   1024

// log-spaced energy table: r = 2^(L0 + k*HL), k in [0,256]; 258 entries/type (pad)
#define TAB_N   258
#define TAB_L0  (-3.3219281f)        // log2(0.1)
#define TAB_HL  (0.017157490f)       // (log2(2.1)-log2(0.1))/256
#define TAB_INV (58.283567f)         // 1/TAB_HL
#define TAB_OFF (193.61423f)         // -L0*TAB_INV

typedef unsigned long long u64;

// ---- poison-immune value-carrying flags: (v, ~v) pairs ----------------------
// ws is re-poisoned each iteration with pattern P: (P,P) can't satisfy
// hi==~lo, so no initialization pass is needed, ever.
__device__ __forceinline__ void pub_pair(u64* p, unsigned v) {
    u64 w = (u64)v | ((u64)(~v) << 32);
    __hip_atomic_store(p, w, __ATOMIC_RELAXED, __HIP_MEMORY_SCOPE_AGENT);
}
template<int SLP>
__device__ __forceinline__ unsigned spin_pair(u64* p) {
    for (;;) {
        u64 w = __hip_atomic_load(p, __ATOMIC_RELAXED, __HIP_MEMORY_SCOPE_AGENT);
        if ((unsigned)(w >> 32) == ~(unsigned)w) return (unsigned)w;
        __builtin_amdgcn_s_sleep(SLP);
    }
}

// =============================================================================
// MEGAKERNEL: pack -> bin -> agg -> red in one dispatch.
// Grid MUST be 512 blocks, all co-resident: LDS ~70.4KB -> 2 blocks/CU;
// __launch_bounds__(1024,8) caps VGPR<=64 -> 2x16 waves/CU. 2*256=512. (R4: held, 96% occ)
// =============================================================================
__global__ __launch_bounds__(P1_TPB, 8) void zbl_mega(
    const float* __restrict__ rij,
    const float* __restrict__ rcov,
    const float* __restrict__ znum,
    const int*  __restrict__ fa,
    const int*  __restrict__ sa,
    const int*  __restrict__ types,
    u64*  __restrict__ packed2,      // [nwords] (word,~word) pairs
    unsigned* __restrict__ counts,   // [NS][P1_BLOCKS] plain (valid after bin barrier)
    u64*  __restrict__ bindone2,     // [P1_BLOCKS] pairs, value = overflow count
    u64*  __restrict__ aggdone2,     // [NS*R_SUB] pairs
    unsigned int* __restrict__ regions, // [P1_BLOCKS][NS][cap]
    uint2* __restrict__ ovf,         // [P1_BLOCKS][ovfStride] {e, atom}
    float* __restrict__ partials,    // [NS][R_SUB][SBS]
    float* __restrict__ out,
    int E, int nquad, int natoms, int nwords, int NS, int cap, int chunkQ,
    int ovfStride)
{
    __shared__ union {
        struct { unsigned pk[NS_MEGA * SBS / 16]; float tabE[16 * TAB_N]; } a; // 69.8 KB
        float  acc[SBS];                                                       // 64 KB
        float4 acc4[SBS / 4];
    } u;
    __shared__ float4 cB[16];
    __shared__ float4 cS[16];
    __shared__ float  cC[16];
    __shared__ int    scnt[NS_MAX];
    __shared__ int    s_ovfn;
    __shared__ int    s_anyovf;

    const int b   = blockIdx.x;
    const int tid = threadIdx.x;

    // ---------------- phase 0: cooperative type-pack (publish pairs) ---------
    {
        int wpb = (nwords + P1_BLOCKS - 1) / P1_BLOCKS;
        int w0 = b * wpb, w1 = w0 + wpb; if (w1 > nwords) w1 = nwords;
        for (int w = w0 + tid; w < w1; w += P1_TPB) {
            int base = w << 4;
            unsigned word = 0;
            #pragma unroll
            for (int j = 0; j < 16; ++j) {
                int i = base + j;
                unsigned t = (i < natoms) ? (unsigned)types[i] : 0u;
                word |= (t & 3u) << (2 * j);
            }
            pub_pair(&packed2[w], word);   // value-carrying flag
        }
    }

    if (tid < NS)  scnt[tid] = 0;
    if (tid == 32) s_ovfn = 0;

    // per-pair constants (16 threads; overlaps other threads' pk spin-load)
    if (tid < 16) {
        const float cc[4] = {0.02817f, 0.28022f, 0.50986f, 0.18175f};
        const float dd[4] = {0.20162f, 0.4029f, 0.94229f, 3.1998f};
        const float COUL = 14.399645478425668f;
        int t = tid;
        int ti = t >> 2, tj = t & 3;
        float zi = znum[ti], zj = znum[tj];
        float rc = rcov[ti] + rcov[tj];
        float a = 0.4685f / (powf(zi, 0.23f) + powf(zj, 0.23f));
        float inva = 1.0f / a;
        float factor = COUL * zi * zj;
        float da[4], ee[4];
        float phi = 0.0f, dphi = 0.0f, d2phi = 0.0f;
        #pragma unroll
        for (int k = 0; k < 4; ++k) {
            da[k] = dd[k] * inva;
            ee[k] = expf(-rc * da[k]);
            phi   += cc[k] * ee[k];
            dphi  -= cc[k] * da[k] * ee[k];
            d2phi += cc[k] * da[k] * da[k] * ee[k];
        }
        float invrc = 1.0f / rc;
        float ec   = factor * invrc * phi;
        float dec  = factor * invrc * (-phi * invrc + dphi);
        float d2ec = factor * invrc * (d2phi - 2.0f * invrc * dphi + 2.0f * phi * invrc * invrc);
        float A = (-3.0f * dec + rc * d2ec) * invrc * invrc;
        float B = (2.0f * dec - rc * d2ec) * invrc * invrc * invrc;
        float Cc = -ec + 0.5f * rc * dec - rc * rc * d2ec * (1.0f / 12.0f);
        const float L2E = 1.4426950408889634f;
        cB[t] = make_float4(rc, 0.5f * factor, A * (1.0f / 6.0f), B * 0.125f);
        cS[t] = make_float4(-da[0] * L2E, -da[1] * L2E, -da[2] * L2E, -da[3] * L2E);
        cC[t] = Cc * 0.5f;
    }

    // spin-load all packed words into LDS (distinct word per thread; brief window)
    for (int w = tid; w < nwords; w += P1_TPB)
        u.a.pk[w] = spin_pair<4>(&packed2[w]);
    __syncthreads();

    const float lc0 = -5.1497481f;   // log2(0.02817)
    const float lc1 = -1.8353434f;   // log2(0.28022)
    const float lc2 = -0.9718340f;   // log2(0.50986)
    const float lc3 = -2.4600449f;   // log2(0.18175)

    // build per-type energy table
    for (int n = tid; n < 16 * TAB_N; n += P1_TPB) {
        int t = n / TAB_N, k = n - t * TAB_N;
        float v = 0.0f;
        if (k <= 256) {
            float r = exp2f(__builtin_fmaf((float)k, TAB_HL, TAB_L0));
            float4 B = cB[t];
            if (r <= B.x) {
                float4 S = cS[t];
                float p = exp2f(__builtin_fmaf(r, S.x, lc0))
                        + exp2f(__builtin_fmaf(r, S.y, lc1))
                        + exp2f(__builtin_fmaf(r, S.z, lc2))
                        + exp2f(__builtin_fmaf(r, S.w, lc3));
                float r3 = r * r * r;
                float poly = __builtin_fmaf(__builtin_fmaf(B.w, r, B.z), r3, cC[t]);
                v = __builtin_fmaf(B.y * p, 1.0f / r, poly);
            }
        }
        u.a.tabE[n] = v;
    }
    __syncthreads();

    // ---------------- phase 1: bin (tabulated e, record scatter) -------------
    {
        const float4* rij4 = (const float4*)rij;
        const int4*   fa4  = (const int4*)fa;
        const int4*   sa4  = (const int4*)sa;
        int myreg = b * NS;
        int q0 = b * chunkQ;
        int q1 = q0 + chunkQ; if (q1 > nquad) q1 = nquad;

        for (int q = q0 + tid; q < q1; q += P1_TPB) {
            float4 rv = rij4[q];
            int4   iv = fa4[q];
            int4   jv = sa4[q];
            float ra[4] = {rv.x, rv.y, rv.z, rv.w};
            int   ia[4] = {iv.x, iv.y, iv.z, iv.w};
            int   ja[4] = {jv.x, jv.y, jv.z, jv.w};
            float eo[4];
            #pragma unroll
            for (int k = 0; k < 4; ++k) {
                int i = ia[k], j = ja[k];
                unsigned wi = u.a.pk[i >> 4], wj = u.a.pk[j >> 4];
                unsigned ti = (wi >> ((i & 15) * 2)) & 3u;
                unsigned tj = (wj >> ((j & 15) * 2)) & 3u;
                int t = (int)((ti << 2) | tj);
                float kf = __builtin_fmaf(__log2f(ra[k]), TAB_INV, TAB_OFF);
                int ki = (int)kf;
                ki = ki < 0 ? 0 : (ki > 256 ? 256 : ki);
                float frac = kf - (float)ki;
                int base = t * TAB_N + ki;
                float v0 = u.a.tabE[base];
                float v1 = u.a.tabE[base + 1];
                eo[k] = __builtin_fmaf(v1 - v0, frac, v0);
            }
            #pragma unroll
            for (int k = 0; k < 4; ++k) {
                if (eo[k] != 0.0f) {
                    int atom = ia[k];
                    int s = atom >> SB_BITS;
                    int slot = atomicAdd(&scnt[s], 1);
                    if (slot < cap) {
                        unsigned rec = ((__float_as_uint(eo[k]) + 0x2000u) & 0xFFFFC000u)
                                     | (unsigned)(atom & (SBS - 1));
                        regions[(myreg + s) * cap + slot] = rec;
                    } else {
                        int o = atomicAdd(&s_ovfn, 1);     // block-local list, no init
                        ovf[(size_t)b * ovfStride + o] =
                            make_uint2(__float_as_uint(eo[k]), (unsigned)atom);
                    }
                }
            }
        }

        // tail edges (E % 4): block 0, into its overflow list
        if (b == 0) {
            for (int idx = nquad * 4 + tid; idx < E; idx += P1_TPB) {
                int i = fa[idx], j = sa[idx];
                unsigned wi = u.a.pk[i >> 4], wj = u.a.pk[j >> 4];
                int t = (int)((((wi >> ((i & 15) * 2)) & 3u) << 2) |
                               ((wj >> ((j & 15) * 2)) & 3u));
                float r = rij[idx];
                float kf = __builtin_fmaf(__log2f(r), TAB_INV, TAB_OFF);
                int ki = (int)kf;
                ki = ki < 0 ? 0 : (ki > 256 ? 256 : ki);
                float frac = kf - (float)ki;
                int base = t * TAB_N + ki;
                float e = __builtin_fmaf(u.a.tabE[base + 1] - u.a.tabE[base], frac,
                                         u.a.tabE[base]);
                if (e != 0.0f) {
                    int o = atomicAdd(&s_ovfn, 1);
                    ovf[(size_t)b * ovfStride + o] =
                        make_uint2(__float_as_uint(e), (unsigned)i);
                }
            }
        }

        // plain counts, then fence, then ONE pair-flag per block (carries ovf count)
        __syncthreads();
        if (tid < NS) counts[tid * P1_BLOCKS + b] = (unsigned)min(scnt[tid], cap);
        __syncthreads();
        if (tid == 0) { __threadfence(); pub_pair(&bindone2[b], (unsigned)s_ovfn); }
    }

    // ---------------- bin barrier: wave 0 polls all 512 flags ----------------
    // 512 polling waves grid-wide (vs R4's 8112), s_sleep(16) cadence.
    if (tid < 64) {
        for (int i = tid; i < P1_BLOCKS; i += 64)
            (void)spin_pair<16>(&bindone2[i]);
    }
    __syncthreads();
    if (tid == 0) __threadfence();           // acquire: counts/regions/ovf fresh
    __syncthreads();

    // ---------------- phase 2: agg (b < NS*R_SUB), zero spinning -------------
    if (b < NS * R_SUB) {
        int s = b / R_SUB, r = b % R_SUB;
        for (int i = tid; i < SBS / 4; i += P1_TPB)
            u.acc4[i] = make_float4(0.f, 0.f, 0.f, 0.f);
        __syncthreads();

        int wave = tid >> 6;
        int lane = tid & 63;
        const int NW = P1_TPB >> 6;            // 16 waves
        for (int p = r + wave * R_SUB; p < P1_BLOCKS; p += NW * R_SUB) {
            unsigned n = counts[s * P1_BLOCKS + p];        // plain, wave-uniform
            int base = (p * NS + s) * cap;
            for (int t = lane; t < (int)n; t += 64) {
                unsigned rec = regions[base + t];
                atomicAdd(&u.acc[rec & (SBS - 1)],
                          __uint_as_float(rec & 0xFFFFC000u));
            }
        }
        __syncthreads();

        float4* dst4 = (float4*)(partials + ((size_t)s * R_SUB + r) * SBS);
        for (int i = tid; i < SBS / 4; i += P1_TPB)
            dst4[i] = u.acc4[i];
        __syncthreads();
        if (tid == 0) { __threadfence(); pub_pair(&aggdone2[b], 1u); }
    }

    // ---------------- phase 3: per-bucket wait, then slice reduction ---------
    {
        int nq  = natoms >> 2;
        int qpb = (nq + P1_BLOCKS - 1) / P1_BLOCKS;
        int qlo = b * qpb, qhi = qlo + qpb;
        if (qlo > nq) qlo = nq;
        if (qhi > nq) qhi = nq;
        int alo = qlo << 2, ahi = qhi << 2;
        bool own_tail = (b == P1_BLOCKS - 1);

        // atom range whose buckets this block must wait on
        int lo = alo, hi = ahi;
        if (own_tail && (natoms & 3)) {
            int t0 = nq << 2;
            if (hi <= lo) { lo = t0; hi = natoms; }
            else          { hi = natoms; }
        }
        if (hi > lo) {
            int s0 = lo >> SB_BITS, s1 = (hi - 1) >> SB_BITS;
            int f0 = s0 * R_SUB, fn = (s1 - s0 + 1) * R_SUB;   // <=117 flags
            if (tid < fn) (void)spin_pair<16>(&aggdone2[f0 + tid]);
        }
        __syncthreads();
        if (tid == 0) __threadfence();       // acquire for partials reads
        __syncthreads();

        for (int q = qlo + tid; q < qhi; q += P1_TPB) {
            int atom = q << 2;
            int s = atom >> SB_BITS, i = atom & (SBS - 1);
            const float* p = partials + (size_t)s * R_SUB * SBS + i;
            float4 acc = make_float4(0.f, 0.f, 0.f, 0.f);
            #pragma unroll
            for (int k = 0; k < R_SUB; ++k) {
                float4 v = *(const float4*)(p + (size_t)k * SBS);
                acc.x += v.x; acc.y += v.y; acc.z += v.z; acc.w += v.w;
            }
            *(float4*)(out + atom) = acc;
        }
        if (own_tail) {
            for (int atom = (nq << 2) + tid; atom < natoms; atom += P1_TPB) {
                int s = atom >> SB_BITS, i = atom & (SBS - 1);
                const float* p = partials + (size_t)s * R_SUB * SBS + i;
                float acc = 0.f;
                #pragma unroll
                for (int k = 0; k < R_SUB; ++k) acc += p[(size_t)k * SBS];
                out[atom] = acc;
            }
        }

        // overflow application (typical count: 0; bindone2 pairs already valid)
        if (tid == 0) s_anyovf = 0;
        __syncthreads();
        for (int p0 = tid; p0 < P1_BLOCKS; p0 += P1_TPB) {
            unsigned n = spin_pair<1>(&bindone2[p0]);
            if (n) atomicAdd(&s_anyovf, (int)n);
        }
        __syncthreads();
        if (s_anyovf > 0) {                    // rare, correctness-only path
            for (int p = 0; p < P1_BLOCKS; ++p) {
                unsigned n = spin_pair<1>(&bindone2[p]);
                const uint2* lst = ovf + (size_t)p * ovfStride;
                for (int e = tid; e < (int)n; e += P1_TPB) {
                    uint2 rec = lst[e];
                    int atom = (int)rec.y;
                    bool mine = (atom >= alo && atom < ahi) ||
                                (own_tail && atom >= (nq << 2) && atom < natoms);
                    if (mine) unsafeAtomicAdd(&out[atom], __uint_as_float(rec.x));
                }
            }
        }
    }
}

// =============================================================================
// LEGACY PATH (natoms > 212992 or tiny ws): known-good 4-kernel pipeline (R3).
// =============================================================================
__global__ __launch_bounds__(TPB_PACK) void zbl_pack(
    const int* __restrict__ types, unsigned int* __restrict__ packed,
    float* __restrict__ fallback, int natoms, int nwords)
{
    int tid = blockIdx.x * TPB_PACK + threadIdx.x;
    int nth = gridDim.x * TPB_PACK;
    for (int w = tid; w < nwords; w += nth) {
        int base = w << 4;
        unsigned int word = 0;
        #pragma unroll
        for (int j = 0; j < 16; ++j) {
            int i = base + j;
            unsigned int t = (i < natoms) ? (unsigned int)types[i] : 0u;
            word |= (t & 3u) << (2 * j);
        }
        packed[w] = word;
    }
    for (int i = tid; i < natoms; i += nth) fallback[i] = 0.0f;
}

__global__ __launch_bounds__(P1_TPB) void zbl_bin(
    const float* __restrict__ rij, const float* __restrict__ rcov,
    const float* __restrict__ znum, const int* __restrict__ fa,
    const int* __restrict__ sa, const unsigned int* __restrict__ packed,
    unsigned int* __restrict__ regions, int* __restrict__ counts,
    float* __restrict__ fallback,
    int E, int nquad, int natoms, int nwords, int NS, int cap, int chunkQ)
{
    extern __shared__ unsigned int s_packed[];
    __shared__ float  tabE[16 * TAB_N];
    __shared__ float4 cB[16];
    __shared__ float4 cS[16];
    __shared__ float  cC[16];
    __shared__ int scnt[NS_MAX];

    for (int w = threadIdx.x; w < nwords; w += P1_TPB) s_packed[w] = packed[w];
    if (threadIdx.x < NS) scnt[threadIdx.x] = 0;

    if (threadIdx.x < 16) {
        const float cc[4] = {0.02817f, 0.28022f, 0.50986f, 0.18175f};
        const float dd[4] = {0.20162f, 0.4029f, 0.94229f, 3.1998f};
        const float COUL = 14.399645478425668f;
        int t = threadIdx.x;
        int ti = t >> 2, tj = t & 3;
        float zi = znum[ti], zj = znum[tj];
        float rc = rcov[ti] + rcov[tj];
        float a = 0.4685f / (powf(zi, 0.23f) + powf(zj, 0.23f));
        float inva = 1.0f / a;
        float factor = COUL * zi * zj;
        float da[4], ee[4];
        float phi = 0.0f, dphi = 0.0f, d2phi = 0.0f;
        #pragma unroll
        for (int k = 0; k < 4; ++k) {
            da[k] = dd[k] * inva;
            ee[k] = expf(-rc * da[k]);
            phi   += cc[k] * ee[k];
            dphi  -= cc[k] * da[k] * ee[k];
            d2phi += cc[k] * da[k] * da[k] * ee[k];
        }
        float invrc = 1.0f / rc;
        float ec   = factor * invrc * phi;
        float dec  = factor * invrc * (-phi * invrc + dphi);
        float d2ec = factor * invrc * (d2phi - 2.0f * invrc * dphi + 2.0f * phi * invrc * invrc);
        float A = (-3.0f * dec + rc * d2ec) * invrc * invrc;
        float B = (2.0f * dec - rc * d2ec) * invrc * invrc * invrc;
        float Cc = -ec + 0.5f * rc * dec - rc * rc * d2ec * (1.0f / 12.0f);
        const float L2E = 1.4426950408889634f;
        cB[t] = make_float4(rc, 0.5f * factor, A * (1.0f / 6.0f), B * 0.125f);
        cS[t] = make_float4(-da[0] * L2E, -da[1] * L2E, -da[2] * L2E, -da[3] * L2E);
        cC[t] = Cc * 0.5f;
    }
    __syncthreads();

    const float lc0 = -5.1497481f, lc1 = -1.8353434f;
    const float lc2 = -0.9718340f, lc3 = -2.4600449f;

    for (int n = threadIdx.x; n < 16 * TAB_N; n += P1_TPB) {
        int t = n / TAB_N, k = n - t * TAB_N;
        float v = 0.0f;
        if (k <= 256) {
            float r = exp2f(__builtin_fmaf((float)k, TAB_HL, TAB_L0));
            float4 B = cB[t];
            if (r <= B.x) {
                float4 S = cS[t];
                float p = exp2f(__builtin_fmaf(r, S.x, lc0))
                        + exp2f(__builtin_fmaf(r, S.y, lc1))
                        + exp2f(__builtin_fmaf(r, S.z, lc2))
                        + exp2f(__builtin_fmaf(r, S.w, lc3));
                float r3 = r * r * r;
                float poly = __builtin_fmaf(__builtin_fmaf(B.w, r, B.z), r3, cC[t]);
                v = __builtin_fmaf(B.y * p, 1.0f / r, poly);
            }
        }
        tabE[n] = v;
    }
    __syncthreads();

    const float4* rij4 = (const float4*)rij;
    const int4*   fa4  = (const int4*)fa;
    const int4*   sa4  = (const int4*)sa;
    int myreg = blockIdx.x * NS;
    int q0 = blockIdx.x * chunkQ;
    int q1 = q0 + chunkQ; if (q1 > nquad) q1 = nquad;

    for (int q = q0 + threadIdx.x; q < q1; q += P1_TPB) {
        float4 rv = rij4[q];
        int4   iv = fa4[q];
        int4   jv = sa4[q];
        float ra[4] = {rv.x, rv.y, rv.z, rv.w};
        int   ia[4] = {iv.x, iv.y, iv.z, iv.w};
        int   ja[4] = {jv.x, jv.y, jv.z, jv.w};
        float eo[4];
        #pragma unroll
        for (int k = 0; k < 4; ++k) {
            int i = ia[k], j = ja[k];
            unsigned int wi = s_packed[i >> 4], wj = s_packed[j >> 4];
            unsigned int ti = (wi >> ((i & 15) * 2)) & 3u;
            unsigned int tj = (wj >> ((j & 15) * 2)) & 3u;
            int t = (int)((ti << 2) | tj);
            float kf = __builtin_fmaf(__log2f(ra[k]), TAB_INV, TAB_OFF);
            int ki = (int)kf;
            ki = ki < 0 ? 0 : (ki > 256 ? 256 : ki);
            float frac = kf - (float)ki;
            int base = t * TAB_N + ki;
            float v0 = tabE[base], v1 = tabE[base + 1];
            eo[k] = __builtin_fmaf(v1 - v0, frac, v0);
        }
        #pragma unroll
        for (int k = 0; k < 4; ++k) {
            if (eo[k] != 0.0f) {
                int atom = ia[k];
                int s = atom >> SB_BITS;
                int slot = atomicAdd(&scnt[s], 1);
                if (slot < cap) {
                    unsigned rec = ((__float_as_uint(eo[k]) + 0x2000u) & 0xFFFFC000u)
                                 | (unsigned)(atom & (SBS - 1));
                    regions[(unsigned)((myreg + s) * cap + slot)] = rec;
                } else {
                    unsafeAtomicAdd(&fallback[atom], eo[k]);
                }
            }
        }
    }

    if (blockIdx.x == 0) {
        for (int idx = nquad * 4 + threadIdx.x; idx < E; idx += P1_TPB) {
            int i = fa[idx], j = sa[idx];
            unsigned int wi = s_packed[i >> 4], wj = s_packed[j >> 4];
            int t = (int)((((wi >> ((i & 15) * 2)) & 3u) << 2) |
                           ((wj >> ((j & 15) * 2)) & 3u));
            float r = rij[idx];
            float kf = __builtin_fmaf(__log2f(r), TAB_INV, TAB_OFF);
            int ki = (int)kf;
            ki = ki < 0 ? 0 : (ki > 256 ? 256 : ki);
            float frac = kf - (float)ki;
            int base = t * TAB_N + ki;
            float e = __builtin_fmaf(tabE[base + 1] - tabE[base], frac, tabE[base]);
            if (e != 0.0f) unsafeAtomicAdd(&fallback[i], e);
        }
    }

    __syncthreads();
    if (cap > 0 && threadIdx.x < NS)
        counts[threadIdx.x * P1_BLOCKS + blockIdx.x] = min(scnt[threadIdx.x], cap);
}

__global__ __launch_bounds__(P2_TPB) void zbl_agg(
    const unsigned int* __restrict__ regions, const int* __restrict__ counts,
    float* __restrict__ partials, int NS, int cap)
{
    __shared__ float acc[SBS];
    int s = blockIdx.x, r = blockIdx.y;
    float4* acc4 = (float4*)acc;
    for (int i = threadIdx.x; i < SBS / 4; i += P2_TPB)
        acc4[i] = make_float4(0.f, 0.f, 0.f, 0.f);
    __syncthreads();
    int wave = threadIdx.x >> 6, lane = threadIdx.x & 63;
    const int NW = P2_TPB >> 6;
    for (int p = r + wave * R_SUB; p < P1_BLOCKS; p += NW * R_SUB) {
        int n = counts[s * P1_BLOCKS + p];
        size_t base = ((size_t)p * NS + s) * (size_t)cap;
        for (int t = lane; t < n; t += 64) {
            unsigned rec = regions[base + t];
            atomicAdd(&acc[rec & (SBS - 1)], __uint_as_float(rec & 0xFFFFC000u));
        }
    }
    __syncthreads();
    float4* dst4 = (float4*)(partials + ((size_t)s * R_SUB + r) * SBS);
    for (int i = threadIdx.x; i < SBS / 4; i += P2_TPB)
        dst4[i] = acc4[i];
}

__global__ __launch_bounds__(TPB_RED) void zbl_red(
    const float* __restrict__ partials, const float* __restrict__ fallback,
    float* __restrict__ out, int natoms)
{
    int q = blockIdx.x * TPB_RED + threadIdx.x;
    int nq = natoms >> 2;
    if (q < nq) {
        int atom = q << 2;
        int s = atom >> SB_BITS, i = atom & (SBS - 1);
        const float4* fb4 = (const float4*)(fallback + atom);
        float4 acc = *fb4;
        const float* p = partials + (size_t)s * R_SUB * SBS + i;
        #pragma unroll
        for (int k = 0; k < R_SUB; ++k) {
            float4 v = *(const float4*)(p + (size_t)k * SBS);
            acc.x += v.x; acc.y += v.y; acc.z += v.z; acc.w += v.w;
        }
        *(float4*)(out + atom) = acc;
    }
    if (blockIdx.x == 0 && threadIdx.x < (natoms & 3)) {
        int atom = (nq << 2) + threadIdx.x;
        int s = atom >> SB_BITS, i = atom & (SBS - 1);
        float acc = fallback[atom];
        const float* p = partials + (size_t)s * R_SUB * SBS + i;
        #pragma unroll
        for (int k = 0; k < R_SUB; ++k) acc += p[(size_t)k * SBS];
        out[atom] = acc;
    }
}

// =============================================================================
static inline size_t al256(size_t x) { return (x + 255) & ~(size_t)255; }

extern "C" void kernel_launch(void* const* d_in, const int* in_sizes, int n_in,
                              void* d_out, int out_size, void* d_ws, size_t ws_size,
                              hipStream_t stream) {
    const float* rij  = (const float*)d_in[0];
    const float* rcov = (const float*)d_in[1];
    const float* znum = (const float*)d_in[2];
    const int*   fa   = (const int*)d_in[3];
    const int*   sa   = (const int*)d_in[4];
    const int*   types= (const int*)d_in[5];
    float* out = (float*)d_out;
    int E = in_sizes[0];
    int natoms = out_size;
    int nquad = E / 4;
    int nwords = (natoms + 15) / 16;
    int NS = (natoms + SBS - 1) >> SB_BITS;
    if (NS > NS_MAX) NS = NS_MAX;
    int chunkQ = (nquad + P1_BLOCKS - 1) / P1_BLOCKS;
    int ovfStride = chunkQ * 4 + 8;

    if (natoms <= NS_MEGA * SBS) {
        // --- mega layout: [packed2][counts][bindone2][aggdone2][partials][ovf][regions]
        size_t packed2_b = al256((size_t)nwords * 8);
        size_t counts_b  = al256((size_t)NS * P1_BLOCKS * 4);
        size_t bind_b    = al256((size_t)P1_BLOCKS * 8);
        size_t aggd_b    = al256((size_t)NS * R_SUB * 8);
        size_t part_b    = al256((size_t)NS * R_SUB * SBS * 4);
        size_t ovf_b     = al256((size_t)P1_BLOCKS * ovfStride * 8);
        char* base = (char*)d_ws;
        u64*  packed2 = (u64*)base;                          base += packed2_b;
        unsigned* counts = (unsigned*)base;                  base += counts_b;
        u64*  bindone2 = (u64*)base;                         base += bind_b;
        u64*  aggdone2 = (u64*)base;                         base += aggd_b;
        float* partials = (float*)base;                      base += part_b;
        uint2* ovf    = (uint2*)base;                        base += ovf_b;
        unsigned int* regions = (unsigned int*)base;

        long long avail = (long long)ws_size
            - (long long)(packed2_b + counts_b + bind_b + aggd_b + part_b + ovf_b);
        int cap = 0;
        if (avail > 0) cap = (int)(avail / ((long long)P1_BLOCKS * NS * 4));
        if (cap > CAP_MAX) cap = CAP_MAX;

        if (cap >= 64) {
            zbl_mega<<<P1_BLOCKS, P1_TPB, 0, stream>>>(
                rij, rcov, znum, fa, sa, types,
                packed2, counts, bindone2, aggdone2, regions, ovf, partials, out,
                E, nquad, natoms, nwords, NS, cap, chunkQ, ovfStride);
            return;
        }
        // fall through to legacy if ws too small
    }

    // --- legacy layout: [packed][counts][fallback][partials][regions]
    size_t packed_bytes = al256((size_t)nwords * 4);
    size_t cnt_bytes    = al256((size_t)NS * P1_BLOCKS * 4);
    size_t fb_bytes     = al256((size_t)natoms * 4);
    size_t part_bytes   = al256((size_t)NS * R_SUB * SBS * 4);
    unsigned int* packed = (unsigned int*)d_ws;
    int*   counts   = (int*)  ((char*)d_ws + packed_bytes);
    float* fallback = (float*)((char*)d_ws + packed_bytes + cnt_bytes);
    float* partials = (float*)((char*)d_ws + packed_bytes + cnt_bytes + fb_bytes);
    unsigned int* regions = (unsigned int*)((char*)d_ws + packed_bytes + cnt_bytes
                                            + fb_bytes + part_bytes);
    long long avail = (long long)ws_size
                    - (long long)(packed_bytes + cnt_bytes + fb_bytes + part_bytes);
    int cap = 0;
    if (avail > 0) cap = (int)(avail / ((long long)P1_BLOCKS * (long long)NS * 4));
    if (cap > CAP_MAX) cap = CAP_MAX;
    size_t smem = (size_t)nwords * sizeof(unsigned int);

    if (cap >= 64) {
        zbl_pack<<<96, TPB_PACK, 0, stream>>>(types, packed, fallback, natoms, nwords);
        zbl_bin<<<P1_BLOCKS, P1_TPB, smem, stream>>>(
            rij, rcov, znum, fa, sa, packed, regions, counts, fallback,
            E, nquad, natoms, nwords, NS, cap, chunkQ);
        dim3 g2(NS, R_SUB);
        zbl_agg<<<g2, P2_TPB, 0, stream>>>(regions, counts, partials, NS, cap);
        int nq = natoms >> 2;
        zbl_red<<<(nq + TPB_RED - 1) / TPB_RED, TPB_RED, 0, stream>>>(
            partials, fallback, out, natoms);
    } else {
        zbl_pack<<<96, TPB_PACK, 0, stream>>>(types, packed, out, natoms, nwords);
        zbl_bin<<<P1_BLOCKS, P1_TPB, smem, stream>>>(
            rij, rcov, znum, fa, sa, packed, regions, counts, out,
            E, nquad, natoms, nwords, NS, 0, chunkQ);
    }
}

// Round 7
// 175.035 us; speedup vs baseline: 2.4374x; 1.3057x over previous
//
#include <hip/hip_runtime.h>

// ---------------------------------------------------------------------------
// Session history:
//  R1: atomic dump to L3-resident out = 135 us (cross-XCD atomic RMW serializes
//      at the coherence point). Keep streaming partials.
//  R2/R3: scnt-alloc variants neutral -> bin store path not the bottleneck.
//  R0-R3 accounting: {fill 41, pack 1.5, bin ~38, agg 10, red 6, GAP ~13/disp}.
//  R4: mega 354 us (spin storm). R5: mega 144 us (fence storm remains) --
//      mega TOTAL 228 > legacy 162 -> megakernel line closed.
//  R6: removed consumer fences -> container died: poison fill pre-touches ws on
//      ALL XCDs, so consumer L2 holds dirty poison lines; without buffer_inv a
//      consumer spins on stale poison forever. Consumer invalidate was load-
//      bearing. LESSON: under re-poison, cross-XCD handoff needs kernel-boundary
//      coherence (or full acquire fences, which cost ~90 us grid-wide).
//  R7 (this): classic pipeline, 4 dispatches (was 5): pack fused into bin
//      (types packed per-block from L2), fallback buffer replaced by per-block
//      ovf lists (no pre-zero needed) applied in red. No inter-block sync.
// ---------------------------------------------------------------------------

#define TPB_PACK  256
#define P1_BLOCKS 512
#define P1_TPB    1024
#define SB_BITS   14
#define SBS       (1 << SB_BITS)     // atoms per super-bucket (16384)
#define NS_FUSE   13                 // fused path: natoms <= 13*16384 = 212992
#define NS_MAX    16
#define P2_TPB    1024
#define R_SUB     39                 // 13*39=507 agg blocks; ~2/CU (R13: fewer regressed)
#define TPB_RED   256
#define CAP_MAX   1024

// log-spaced energy table: r = 2^(L0 + k*HL), k in [0,256]; 258 entries/type (pad)
#define TAB_N   258
#define TAB_L0  (-3.3219281f)        // log2(0.1)
#define TAB_HL  (0.017157490f)       // (log2(2.1)-log2(0.1))/256
#define TAB_INV (58.283567f)         // 1/TAB_HL
#define TAB_OFF (193.61423f)         // -L0*TAB_INV

// =============================================================================
// FUSED Phase 1: pack types (per-block, from L2-resident types[]) + tabulated
// e(r,t) + record scatter. counts has NS+1 rows; row NS = per-block ovf count.
// =============================================================================
__global__ __launch_bounds__(P1_TPB) void zbl_bin3(
    const float* __restrict__ rij,
    const float* __restrict__ rcov,
    const float* __restrict__ znum,
    const int*  __restrict__ fa,
    const int*  __restrict__ sa,
    const int*  __restrict__ types,
    unsigned int* __restrict__ regions,  // [P1_BLOCKS][NS][cap]
    int*   __restrict__ counts,          // [(NS+1)][P1_BLOCKS]
    uint2* __restrict__ ovf,             // [P1_BLOCKS][ovfStride]
    int E, int nquad, int natoms, int nwords, int NS, int cap, int chunkQ,
    int ovfStride)
{
    __shared__ unsigned s_pk[NS_FUSE * SBS / 16];   // 53.2 KB
    __shared__ float  tabE[16 * TAB_N];             // 16.5 KB
    __shared__ float4 cB[16];
    __shared__ float4 cS[16];
    __shared__ float  cC[16];
    __shared__ int    scnt[NS_MAX];
    __shared__ int    s_ovfn;

    const int b   = blockIdx.x;
    const int tid = threadIdx.x;

    if (tid < NS)  scnt[tid] = 0;
    if (tid == 32) s_ovfn = 0;

    // pack types -> LDS directly (L2-resident after first reads; no pack kernel)
    {
        const int4* t4 = (const int4*)types;
        for (int w = tid; w < nwords; w += P1_TPB) {
            unsigned word = 0;
            if (((w << 4) + 16) <= natoms) {        // fast path: 4x int4
                int b4 = w << 2;
                #pragma unroll
                for (int g = 0; g < 4; ++g) {
                    int4 v = t4[b4 + g];
                    word |= ((unsigned)v.x & 3u) << (8 * g + 0);
                    word |= ((unsigned)v.y & 3u) << (8 * g + 2);
                    word |= ((unsigned)v.z & 3u) << (8 * g + 4);
                    word |= ((unsigned)v.w & 3u) << (8 * g + 6);
                }
            } else {                                 // ragged last word
                int base = w << 4;
                for (int j = 0; j < 16; ++j) {
                    int i = base + j;
                    unsigned t = (i < natoms) ? (unsigned)types[i] : 0u;
                    word |= (t & 3u) << (2 * j);
                }
            }
            s_pk[w] = word;
        }
    }

    // per-pair constants
    if (tid < 16) {
        const float cc[4] = {0.02817f, 0.28022f, 0.50986f, 0.18175f};
        const float dd[4] = {0.20162f, 0.4029f, 0.94229f, 3.1998f};
        const float COUL = 14.399645478425668f;
        int t = tid;
        int ti = t >> 2, tj = t & 3;
        float zi = znum[ti], zj = znum[tj];
        float rc = rcov[ti] + rcov[tj];
        float a = 0.4685f / (powf(zi, 0.23f) + powf(zj, 0.23f));
        float inva = 1.0f / a;
        float factor = COUL * zi * zj;
        float da[4], ee[4];
        float phi = 0.0f, dphi = 0.0f, d2phi = 0.0f;
        #pragma unroll
        for (int k = 0; k < 4; ++k) {
            da[k] = dd[k] * inva;
            ee[k] = expf(-rc * da[k]);
            phi   += cc[k] * ee[k];
            dphi  -= cc[k] * da[k] * ee[k];
            d2phi += cc[k] * da[k] * da[k] * ee[k];
        }
        float invrc = 1.0f / rc;
        float ec   = factor * invrc * phi;
        float dec  = factor * invrc * (-phi * invrc + dphi);
        float d2ec = factor * invrc * (d2phi - 2.0f * invrc * dphi + 2.0f * phi * invrc * invrc);
        float A = (-3.0f * dec + rc * d2ec) * invrc * invrc;
        float B = (2.0f * dec - rc * d2ec) * invrc * invrc * invrc;
        float Cc = -ec + 0.5f * rc * dec - rc * rc * d2ec * (1.0f / 12.0f);
        const float L2E = 1.4426950408889634f;
        cB[t] = make_float4(rc, 0.5f * factor, A * (1.0f / 6.0f), B * 0.125f);
        cS[t] = make_float4(-da[0] * L2E, -da[1] * L2E, -da[2] * L2E, -da[3] * L2E);
        cC[t] = Cc * 0.5f;
    }
    __syncthreads();

    const float lc0 = -5.1497481f;   // log2(0.02817)
    const float lc1 = -1.8353434f;   // log2(0.28022)
    const float lc2 = -0.9718340f;   // log2(0.50986)
    const float lc3 = -2.4600449f;   // log2(0.18175)

    // build per-type energy table
    for (int n = tid; n < 16 * TAB_N; n += P1_TPB) {
        int t = n / TAB_N, k = n - t * TAB_N;
        float v = 0.0f;
        if (k <= 256) {
            float r = exp2f(__builtin_fmaf((float)k, TAB_HL, TAB_L0));
            float4 B = cB[t];
            if (r <= B.x) {
                float4 S = cS[t];
                float p = exp2f(__builtin_fmaf(r, S.x, lc0))
                        + exp2f(__builtin_fmaf(r, S.y, lc1))
                        + exp2f(__builtin_fmaf(r, S.z, lc2))
                        + exp2f(__builtin_fmaf(r, S.w, lc3));
                float r3 = r * r * r;
                float poly = __builtin_fmaf(__builtin_fmaf(B.w, r, B.z), r3, cC[t]);
                v = __builtin_fmaf(B.y * p, 1.0f / r, poly);
            }
        }
        tabE[n] = v;
    }
    __syncthreads();

    const float4* rij4 = (const float4*)rij;
    const int4*   fa4  = (const int4*)fa;
    const int4*   sa4  = (const int4*)sa;
    int myreg = b * NS;
    int q0 = b * chunkQ;
    int q1 = q0 + chunkQ; if (q1 > nquad) q1 = nquad;

    for (int q = q0 + tid; q < q1; q += P1_TPB) {
        float4 rv = rij4[q];
        int4   iv = fa4[q];
        int4   jv = sa4[q];
        float ra[4] = {rv.x, rv.y, rv.z, rv.w};
        int   ia[4] = {iv.x, iv.y, iv.z, iv.w};
        int   ja[4] = {jv.x, jv.y, jv.z, jv.w};
        float eo[4];
        #pragma unroll
        for (int k = 0; k < 4; ++k) {
            int i = ia[k], j = ja[k];
            unsigned wi = s_pk[i >> 4], wj = s_pk[j >> 4];
            unsigned ti = (wi >> ((i & 15) * 2)) & 3u;
            unsigned tj = (wj >> ((j & 15) * 2)) & 3u;
            int t = (int)((ti << 2) | tj);
            // log-spaced table lookup: branchless, no exp, no rc test
            float kf = __builtin_fmaf(__log2f(ra[k]), TAB_INV, TAB_OFF);
            int ki = (int)kf;
            ki = ki < 0 ? 0 : (ki > 256 ? 256 : ki);
            float frac = kf - (float)ki;
            int base = t * TAB_N + ki;
            float v0 = tabE[base];          // ds_read2_b32 pair
            float v1 = tabE[base + 1];
            eo[k] = __builtin_fmaf(v1 - v0, frac, v0);
        }
        #pragma unroll
        for (int k = 0; k < 4; ++k) {
            if (eo[k] != 0.0f) {
                int atom = ia[k];
                int s = atom >> SB_BITS;
                int slot = atomicAdd(&scnt[s], 1);
                if (slot < cap) {
                    unsigned rec = ((__float_as_uint(eo[k]) + 0x2000u) & 0xFFFFC000u)
                                 | (unsigned)(atom & (SBS - 1));
                    regions[(unsigned)((myreg + s) * cap + slot)] = rec;
                } else {
                    int o = atomicAdd(&s_ovfn, 1);   // block-local list, no init
                    ovf[(size_t)b * ovfStride + o] =
                        make_uint2(__float_as_uint(eo[k]), (unsigned)atom);
                }
            }
        }
    }

    // tail edges (E % 4 != 0): block 0, into its overflow list (<=3 entries)
    if (b == 0) {
        for (int idx = nquad * 4 + tid; idx < E; idx += P1_TPB) {
            int i = fa[idx], j = sa[idx];
            unsigned wi = s_pk[i >> 4], wj = s_pk[j >> 4];
            int t = (int)((((wi >> ((i & 15) * 2)) & 3u) << 2) |
                           ((wj >> ((j & 15) * 2)) & 3u));
            float r = rij[idx];
            float kf = __builtin_fmaf(__log2f(r), TAB_INV, TAB_OFF);
            int ki = (int)kf;
            ki = ki < 0 ? 0 : (ki > 256 ? 256 : ki);
            float frac = kf - (float)ki;
            int base = t * TAB_N + ki;
            float e = __builtin_fmaf(tabE[base + 1] - tabE[base], frac, tabE[base]);
            if (e != 0.0f) {
                int o = atomicAdd(&s_ovfn, 1);
                ovf[(size_t)b * ovfStride + o] =
                    make_uint2(__float_as_uint(e), (unsigned)i);
            }
        }
    }

    __syncthreads();
    if (tid < NS)  counts[tid * P1_BLOCKS + b] = min(scnt[tid], cap);
    if (tid == NS) counts[NS  * P1_BLOCKS + b] = s_ovfn;
}

// ------- Phase 2: (super-bucket, replica) -> 64 KB LDS accumulator -------
__global__ __launch_bounds__(P2_TPB) void zbl_agg(
    const unsigned int* __restrict__ regions,
    const int*  __restrict__ counts,     // [(NS+1)][P1_BLOCKS]; rows 0..NS-1 used
    float* __restrict__ partials,        // [NS][R_SUB][SBS]
    int NS, int cap)
{
    __shared__ float acc[SBS];           // 64 KB -> 2 blocks/CU
    int s = blockIdx.x, r = blockIdx.y;
    float4* acc4 = (float4*)acc;
    for (int i = threadIdx.x; i < SBS / 4; i += P2_TPB)
        acc4[i] = make_float4(0.f, 0.f, 0.f, 0.f);
    __syncthreads();
    int wave = threadIdx.x >> 6, lane = threadIdx.x & 63;
    const int NW = P2_TPB >> 6;          // 16 waves
    for (int p = r + wave * R_SUB; p < P1_BLOCKS; p += NW * R_SUB) {
        int n = counts[s * P1_BLOCKS + p];               // wave-uniform load
        size_t base = ((size_t)p * NS + s) * (size_t)cap;
        for (int t = lane; t < n; t += 64) {
            unsigned rec = regions[base + t];            // coalesced 256 B/wave
            atomicAdd(&acc[rec & (SBS - 1)],
                      __uint_as_float(rec & 0xFFFFC000u));   // ds_add_f32
        }
    }
    __syncthreads();
    float4* dst4 = (float4*)(partials + ((size_t)s * R_SUB + r) * SBS);
    for (int i = threadIdx.x; i < SBS / 4; i += P2_TPB)
        dst4[i] = acc4[i];
}

// ------- Phase 3: reduce R_SUB partials (+ rare ovf entries) -> out -------
__global__ __launch_bounds__(TPB_RED) void zbl_red3(
    const float* __restrict__ partials,
    const int*   __restrict__ counts,    // row NS = per-producer ovf counts
    const uint2* __restrict__ ovf,
    float* __restrict__ out,
    int natoms, int NS, int ovfStride)
{
    __shared__ int s_any;
    int tid = threadIdx.x;
    int q = blockIdx.x * TPB_RED + tid;  // quad-of-atoms index
    int nq = natoms >> 2;

    float4 acc = make_float4(0.f, 0.f, 0.f, 0.f);
    int atom0 = q << 2;
    if (q < nq) {
        int s = atom0 >> SB_BITS, i = atom0 & (SBS - 1);  // quad never crosses buckets
        const float* p = partials + (size_t)s * R_SUB * SBS + i;
        #pragma unroll
        for (int k = 0; k < R_SUB; ++k) {
            float4 v = *(const float4*)(p + (size_t)k * SBS);
            acc.x += v.x; acc.y += v.y; acc.z += v.z; acc.w += v.w;
        }
    }

    // overflow detection (typical: s_any == 0, everything below is skipped)
    if (tid == 0) s_any = 0;
    __syncthreads();
    for (int p0 = tid; p0 < P1_BLOCKS; p0 += TPB_RED) {
        int n = counts[NS * P1_BLOCKS + p0];
        if (n > 0) atomicAdd(&s_any, n);
    }
    __syncthreads();
    if (s_any > 0 && q < nq) {           // rare, correctness-only path
        for (int p = 0; p < P1_BLOCKS; ++p) {
            int n = counts[NS * P1_BLOCKS + p];
            const uint2* lst = ovf + (size_t)p * ovfStride;
            for (int e = 0; e < n; ++e) {
                uint2 rec = lst[e];
                int d = (int)rec.y - atom0;
                if ((unsigned)d < 4u) {
                    float v = __uint_as_float(rec.x);
                    if      (d == 0) acc.x += v;
                    else if (d == 1) acc.y += v;
                    else if (d == 2) acc.z += v;
                    else             acc.w += v;
                }
            }
        }
    }
    if (q < nq) *(float4*)(out + atom0) = acc;

    // scalar tail (natoms % 4)
    if (blockIdx.x == 0 && tid < (natoms & 3)) {
        int atom = (nq << 2) + tid;
        int s = atom >> SB_BITS, i = atom & (SBS - 1);
        const float* p = partials + (size_t)s * R_SUB * SBS + i;
        float a = 0.f;
        #pragma unroll
        for (int k = 0; k < R_SUB; ++k) a += p[(size_t)k * SBS];
        if (s_any > 0) {
            for (int pp = 0; pp < P1_BLOCKS; ++pp) {
                int n = counts[NS * P1_BLOCKS + pp];
                const uint2* lst = ovf + (size_t)pp * ovfStride;
                for (int e = 0; e < n; ++e)
                    if ((int)lst[e].y == atom) a += __uint_as_float(lst[e].x);
            }
        }
        out[atom] = a;
    }
}

// =============================================================================
// LEGACY PATH (natoms > 212992 or tiny ws): known-good R3 pipeline.
// =============================================================================
__global__ __launch_bounds__(TPB_PACK) void zbl_pack(
    const int* __restrict__ types, unsigned int* __restrict__ packed,
    float* __restrict__ fallback, int natoms, int nwords)
{
    int tid = blockIdx.x * TPB_PACK + threadIdx.x;
    int nth = gridDim.x * TPB_PACK;
    for (int w = tid; w < nwords; w += nth) {
        int base = w << 4;
        unsigned int word = 0;
        #pragma unroll
        for (int j = 0; j < 16; ++j) {
            int i = base + j;
            unsigned int t = (i < natoms) ? (unsigned int)types[i] : 0u;
            word |= (t & 3u) << (2 * j);
        }
        packed[w] = word;
    }
    for (int i = tid; i < natoms; i += nth) fallback[i] = 0.0f;
}

__global__ __launch_bounds__(P1_TPB) void zbl_bin(
    const float* __restrict__ rij, const float* __restrict__ rcov,
    const float* __restrict__ znum, const int* __restrict__ fa,
    const int* __restrict__ sa, const unsigned int* __restrict__ packed,
    unsigned int* __restrict__ regions, int* __restrict__ counts,
    float* __restrict__ fallback,
    int E, int nquad, int natoms, int nwords, int NS, int cap, int chunkQ)
{
    extern __shared__ unsigned int s_packed[];
    __shared__ float  tabE[16 * TAB_N];
    __shared__ float4 cB[16];
    __shared__ float4 cS[16];
    __shared__ float  cC[16];
    __shared__ int scnt[NS_MAX];

    for (int w = threadIdx.x; w < nwords; w += P1_TPB) s_packed[w] = packed[w];
    if (threadIdx.x < NS) scnt[threadIdx.x] = 0;

    if (threadIdx.x < 16) {
        const float cc[4] = {0.02817f, 0.28022f, 0.50986f, 0.18175f};
        const float dd[4] = {0.20162f, 0.4029f, 0.94229f, 3.1998f};
        const float COUL = 14.399645478425668f;
        int t = threadIdx.x;
        int ti = t >> 2, tj = t & 3;
        float zi = znum[ti], zj = znum[tj];
        float rc = rcov[ti] + rcov[tj];
        float a = 0.4685f / (powf(zi, 0.23f) + powf(zj, 0.23f));
        float inva = 1.0f / a;
        float factor = COUL * zi * zj;
        float da[4], ee[4];
        float phi = 0.0f, dphi = 0.0f, d2phi = 0.0f;
        #pragma unroll
        for (int k = 0; k < 4; ++k) {
            da[k] = dd[k] * inva;
            ee[k] = expf(-rc * da[k]);
            phi   += cc[k] * ee[k];
            dphi  -= cc[k] * da[k] * ee[k];
            d2phi += cc[k] * da[k] * da[k] * ee[k];
        }
        float invrc = 1.0f / rc;
        float ec   = factor * invrc * phi;
        float dec  = factor * invrc * (-phi * invrc + dphi);
        float d2ec = factor * invrc * (d2phi - 2.0f * invrc * dphi + 2.0f * phi * invrc * invrc);
        float A = (-3.0f * dec + rc * d2ec) * invrc * invrc;
        float B = (2.0f * dec - rc * d2ec) * invrc * invrc * invrc;
        float Cc = -ec + 0.5f * rc * dec - rc * rc * d2ec * (1.0f / 12.0f);
        const float L2E = 1.4426950408889634f;
        cB[t] = make_float4(rc, 0.5f * factor, A * (1.0f / 6.0f), B * 0.125f);
        cS[t] = make_float4(-da[0] * L2E, -da[1] * L2E, -da[2] * L2E, -da[3] * L2E);
        cC[t] = Cc * 0.5f;
    }
    __syncthreads();

    const float lc0 = -5.1497481f, lc1 = -1.8353434f;
    const float lc2 = -0.9718340f, lc3 = -2.4600449f;

    for (int n = threadIdx.x; n < 16 * TAB_N; n += P1_TPB) {
        int t = n / TAB_N, k = n - t * TAB_N;
        float v = 0.0f;
        if (k <= 256) {
            float r = exp2f(__builtin_fmaf((float)k, TAB_HL, TAB_L0));
            float4 B = cB[t];
            if (r <= B.x) {
                float4 S = cS[t];
                float p = exp2f(__builtin_fmaf(r, S.x, lc0))
                        + exp2f(__builtin_fmaf(r, S.y, lc1))
                        + exp2f(__builtin_fmaf(r, S.z, lc2))
                        + exp2f(__builtin_fmaf(r, S.w, lc3));
                float r3 = r * r * r;
                float poly = __builtin_fmaf(__builtin_fmaf(B.w, r, B.z), r3, cC[t]);
                v = __builtin_fmaf(B.y * p, 1.0f / r, poly);
            }
        }
        tabE[n] = v;
    }
    __syncthreads();

    const float4* rij4 = (const float4*)rij;
    const int4*   fa4  = (const int4*)fa;
    const int4*   sa4  = (const int4*)sa;
    int myreg = blockIdx.x * NS;
    int q0 = blockIdx.x * chunkQ;
    int q1 = q0 + chunkQ; if (q1 > nquad) q1 = nquad;

    for (int q = q0 + threadIdx.x; q < q1; q += P1_TPB) {
        float4 rv = rij4[q];
        int4   iv = fa4[q];
        int4   jv = sa4[q];
        float ra[4] = {rv.x, rv.y, rv.z, rv.w};
        int   ia[4] = {iv.x, iv.y, iv.z, iv.w};
        int   ja[4] = {jv.x, jv.y, jv.z, jv.w};
        float eo[4];
        #pragma unroll
        for (int k = 0; k < 4; ++k) {
            int i = ia[k], j = ja[k];
            unsigned int wi = s_packed[i >> 4], wj = s_packed[j >> 4];
            unsigned int ti = (wi >> ((i & 15) * 2)) & 3u;
            unsigned int tj = (wj >> ((j & 15) * 2)) & 3u;
            int t = (int)((ti << 2) | tj);
            float kf = __builtin_fmaf(__log2f(ra[k]), TAB_INV, TAB_OFF);
            int ki = (int)kf;
            ki = ki < 0 ? 0 : (ki > 256 ? 256 : ki);
            float frac = kf - (float)ki;
            int base = t * TAB_N + ki;
            float v0 = tabE[base], v1 = tabE[base + 1];
            eo[k] = __builtin_fmaf(v1 - v0, frac, v0);
        }
        #pragma unroll
        for (int k = 0; k < 4; ++k) {
            if (eo[k] != 0.0f) {
                int atom = ia[k];
                int s = atom >> SB_BITS;
                int slot = atomicAdd(&scnt[s], 1);
                if (slot < cap) {
                    unsigned rec = ((__float_as_uint(eo[k]) + 0x2000u) & 0xFFFFC000u)
                                 | (unsigned)(atom & (SBS - 1));
                    regions[(unsigned)((myreg + s) * cap + slot)] = rec;
                } else {
                    unsafeAtomicAdd(&fallback[atom], eo[k]);
                }
            }
        }
    }

    if (blockIdx.x == 0) {
        for (int idx = nquad * 4 + threadIdx.x; idx < E; idx += P1_TPB) {
            int i = fa[idx], j = sa[idx];
            unsigned int wi = s_packed[i >> 4], wj = s_packed[j >> 4];
            int t = (int)((((wi >> ((i & 15) * 2)) & 3u) << 2) |
                           ((wj >> ((j & 15) * 2)) & 3u));
            float r = rij[idx];
            float kf = __builtin_fmaf(__log2f(r), TAB_INV, TAB_OFF);
            int ki = (int)kf;
            ki = ki < 0 ? 0 : (ki > 256 ? 256 : ki);
            float frac = kf - (float)ki;
            int base = t * TAB_N + ki;
            float e = __builtin_fmaf(tabE[base + 1] - tabE[base], frac, tabE[base]);
            if (e != 0.0f) unsafeAtomicAdd(&fallback[i], e);
        }
    }

    __syncthreads();
    if (cap > 0 && threadIdx.x < NS)
        counts[threadIdx.x * P1_BLOCKS + blockIdx.x] = min(scnt[threadIdx.x], cap);
}

__global__ __launch_bounds__(TPB_RED) void zbl_red(
    const float* __restrict__ partials, const float* __restrict__ fallback,
    float* __restrict__ out, int natoms)
{
    int q = blockIdx.x * TPB_RED + threadIdx.x;
    int nq = natoms >> 2;
    if (q < nq) {
        int atom = q << 2;
        int s = atom >> SB_BITS, i = atom & (SBS - 1);
        const float4* fb4 = (const float4*)(fallback + atom);
        float4 acc = *fb4;
        const float* p = partials + (size_t)s * R_SUB * SBS + i;
        #pragma unroll
        for (int k = 0; k < R_SUB; ++k) {
            float4 v = *(const float4*)(p + (size_t)k * SBS);
            acc.x += v.x; acc.y += v.y; acc.z += v.z; acc.w += v.w;
        }
        *(float4*)(out + atom) = acc;
    }
    if (blockIdx.x == 0 && threadIdx.x < (natoms & 3)) {
        int atom = (nq << 2) + threadIdx.x;
        int s = atom >> SB_BITS, i = atom & (SBS - 1);
        float acc = fallback[atom];
        const float* p = partials + (size_t)s * R_SUB * SBS + i;
        #pragma unroll
        for (int k = 0; k < R_SUB; ++k) acc += p[(size_t)k * SBS];
        out[atom] = acc;
    }
}

// =============================================================================
static inline size_t al256(size_t x) { return (x + 255) & ~(size_t)255; }

extern "C" void kernel_launch(void* const* d_in, const int* in_sizes, int n_in,
                              void* d_out, int out_size, void* d_ws, size_t ws_size,
                              hipStream_t stream) {
    const float* rij  = (const float*)d_in[0];
    const float* rcov = (const float*)d_in[1];
    const float* znum = (const float*)d_in[2];
    const int*   fa   = (const int*)d_in[3];
    const int*   sa   = (const int*)d_in[4];
    const int*   types= (const int*)d_in[5];
    float* out = (float*)d_out;
    int E = in_sizes[0];
    int natoms = out_size;
    int nquad = E / 4;
    int nwords = (natoms + 15) / 16;
    int NS = (natoms + SBS - 1) >> SB_BITS;      // 13 for 200K atoms
    if (NS > NS_MAX) NS = NS_MAX;
    int chunkQ = (nquad + P1_BLOCKS - 1) / P1_BLOCKS;
    int ovfStride = chunkQ * 4 + 8;

    if (natoms <= NS_FUSE * SBS) {
        // --- fused layout: [counts][ovf][partials][regions]
        size_t cnt_b  = al256((size_t)(NS + 1) * P1_BLOCKS * 4);
        size_t ovf_b  = al256((size_t)P1_BLOCKS * ovfStride * 8);
        size_t part_b = al256((size_t)NS * R_SUB * SBS * 4);
        char* base = (char*)d_ws;
        int*   counts   = (int*)base;                        base += cnt_b;
        uint2* ovf      = (uint2*)base;                      base += ovf_b;
        float* partials = (float*)base;                      base += part_b;
        unsigned int* regions = (unsigned int*)base;

        long long avail = (long long)ws_size - (long long)(cnt_b + ovf_b + part_b);
        int cap = 0;
        if (avail > 0) cap = (int)(avail / ((long long)P1_BLOCKS * NS * 4));
        if (cap > CAP_MAX) cap = CAP_MAX;

        if (cap >= 64) {
            zbl_bin3<<<P1_BLOCKS, P1_TPB, 0, stream>>>(
                rij, rcov, znum, fa, sa, types,
                regions, counts, ovf,
                E, nquad, natoms, nwords, NS, cap, chunkQ, ovfStride);
            dim3 g2(NS, R_SUB);
            zbl_agg<<<g2, P2_TPB, 0, stream>>>(regions, counts, partials, NS, cap);
            int nq = natoms >> 2;
            zbl_red3<<<(nq + TPB_RED - 1) / TPB_RED, TPB_RED, 0, stream>>>(
                partials, counts, ovf, out, natoms, NS, ovfStride);
            return;
        }
        // fall through to legacy if ws too small
    }

    // --- legacy layout: [packed][counts][fallback][partials][regions]
    size_t packed_bytes = al256((size_t)nwords * 4);
    size_t cnt_bytes    = al256((size_t)NS * P1_BLOCKS * 4);
    size_t fb_bytes     = al256((size_t)natoms * 4);
    size_t part_bytes   = al256((size_t)NS * R_SUB * SBS * 4);
    unsigned int* packed = (unsigned int*)d_ws;
    int*   counts   = (int*)  ((char*)d_ws + packed_bytes);
    float* fallback = (float*)((char*)d_ws + packed_bytes + cnt_bytes);
    float* partials = (float*)((char*)d_ws + packed_bytes + cnt_bytes + fb_bytes);
    unsigned int* regions = (unsigned int*)((char*)d_ws + packed_bytes + cnt_bytes
                                            + fb_bytes + part_bytes);
    long long avail = (long long)ws_size
                    - (long long)(packed_bytes + cnt_bytes + fb_bytes + part_bytes);
    int cap = 0;
    if (avail > 0) cap = (int)(avail / ((long long)P1_BLOCKS * (long long)NS * 4));
    if (cap > CAP_MAX) cap = CAP_MAX;
    size_t smem = (size_t)nwords * sizeof(unsigned int);

    if (cap >= 64) {
        zbl_pack<<<96, TPB_PACK, 0, stream>>>(types, packed, fallback, natoms, nwords);
        zbl_bin<<<P1_BLOCKS, P1_TPB, smem, stream>>>(
            rij, rcov, znum, fa, sa, packed, regions, counts, fallback,
            E, nquad, natoms, nwords, NS, cap, chunkQ);
        dim3 g2(NS, R_SUB);
        zbl_agg<<<g2, P2_TPB, 0, stream>>>(regions, counts, partials, NS, cap);
        int nq = natoms >> 2;
        zbl_red<<<(nq + TPB_RED - 1) / TPB_RED, TPB_RED, 0, stream>>>(
            partials, fallback, out, natoms);
    } else {
        zbl_pack<<<96, TPB_PACK, 0, stream>>>(types, packed, out, natoms, nwords);
        zbl_bin<<<P1_BLOCKS, P1_TPB, smem, stream>>>(
            rij, rcov, znum, fa, sa, packed, regions, counts, out,
            E, nquad, natoms, nwords, NS, 0, chunkQ);
    }
}